// Round 7
// baseline (116.756 us; speedup 1.0000x reference)
//
#include <hip/hip_runtime.h>
#include <hip/hip_bf16.h>
#include <hip/hip_fp16.h>

// NodeTypeConcatSheafLearner: out[e] = tanh(concat(x[src],x[dst],oh[src],oh[dst]) @ W^T)
// Factorized: per-node projections quantized to 9 x 14-bit fixed-point
// (scale 128) packed into ONE 16-byte row per node per direction.
// Tables Ts, Td are 1.6 MB each (3.2 MB total) -> L2-resident per XCD; each
// edge does exactly TWO aligned global_load_dwordx4 gathers (one line each).
// Edge kernel processes 4 edges/thread (strided by TPB) -> 8 independent
// gathers in flight per thread for latency hiding; LDS tile stays in linear
// edge order (lane stride 9 dwords = 2-way bank aliasing, free).
// Error bound: quant 0.5/128 per operand, exact int add -> |out err| <= 1/128.

#define ODIM 9      // 3*3 output maps per edge
#define INF 72      // 2*32 + 2*4 input features of W rows
#define TPB 256
#define EPT 4       // edges per thread in edge_kernel
#define QSCALE 128.0f

typedef unsigned int uint4n __attribute__((ext_vector_type(4)));
typedef float float4n __attribute__((ext_vector_type(4)));

// tanh(q/128) = 1 - 2/(exp2(q*c)+1), c = 2*log2(e)/128
#define TANH_C (2.0f * 1.4426950408889634f / QSCALE)

__device__ __forceinline__ float tanh_from_q(int q) {
    float e = __builtin_exp2f((float)q * TANH_C);
    return 1.0f - 2.0f * __builtin_amdgcn_rcpf(e + 1.0f);
}

__device__ __forceinline__ int quant14(float v) {
    int q = __float2int_rn(v * QSCALE);
    return min(max(q, -8191), 8191);
}

__device__ __forceinline__ unsigned pk(int lo, int hi, unsigned nib) {
    return (unsigned)(lo & 0x3fff) | ((unsigned)(hi & 0x3fff) << 14) | (nib << 28);
}

__device__ __forceinline__ void unpack9(uint4n r, int* q) {
    q[0] = ((int)(r.x << 18)) >> 18;
    q[1] = ((int)(r.x <<  4)) >> 18;
    q[2] = ((int)(r.y << 18)) >> 18;
    q[3] = ((int)(r.y <<  4)) >> 18;
    q[4] = ((int)(r.z << 18)) >> 18;
    q[5] = ((int)(r.z <<  4)) >> 18;
    q[6] = ((int)(r.w << 18)) >> 18;
    q[7] = ((int)(r.w <<  4)) >> 18;
    unsigned u = (r.x >> 28) | ((r.y >> 28) << 4) |
                 ((r.z >> 28) << 8) | ((r.w >> 28) << 12);
    q[8] = ((int)(u << 18)) >> 18;
}

__global__ __launch_bounds__(TPB) void node_proj_kernel(
        const float* __restrict__ x, const int* __restrict__ nt,
        const float* __restrict__ W, uint4n* __restrict__ Ts,
        uint4n* __restrict__ Td, int N) {
    int n = blockIdx.x * TPB + threadIdx.x;
    if (n >= N) return;
    float xv[32];
    const float4n* xp = (const float4n*)(x + (size_t)n * 32);
    #pragma unroll
    for (int i = 0; i < 8; ++i) {
        float4n r = __builtin_nontemporal_load(xp + i);
        xv[4*i+0] = r.x; xv[4*i+1] = r.y; xv[4*i+2] = r.z; xv[4*i+3] = r.w;
    }
    int ty = nt[n];
    int qs[9], qd[9];
    #pragma unroll
    for (int o = 0; o < ODIM; ++o) {
        const float* wr = W + o * INF;  // wave-uniform base -> scalar loads
        float s1 = wr[64 + ty];         // one-hot(src type) contribution
        float s2 = wr[68 + ty];         // one-hot(dst type) contribution
        #pragma unroll
        for (int f = 0; f < 32; ++f) {
            s1 += xv[f] * wr[f];
            s2 += xv[f] * wr[32 + f];
        }
        qs[o] = quant14(s1);
        qd[o] = quant14(s2);
    }
    uint4n a, b;
    a.x = pk(qs[0], qs[1],  (unsigned)qs[8]        & 0xf);
    a.y = pk(qs[2], qs[3], ((unsigned)qs[8] >>  4) & 0xf);
    a.z = pk(qs[4], qs[5], ((unsigned)qs[8] >>  8) & 0xf);
    a.w = pk(qs[6], qs[7], ((unsigned)qs[8] >> 12) & 0x3);
    b.x = pk(qd[0], qd[1],  (unsigned)qd[8]        & 0xf);
    b.y = pk(qd[2], qd[3], ((unsigned)qd[8] >>  4) & 0xf);
    b.z = pk(qd[4], qd[5], ((unsigned)qd[8] >>  8) & 0xf);
    b.w = pk(qd[6], qd[7], ((unsigned)qd[8] >> 12) & 0x3);
    Ts[n] = a;  // 16B/thread, fully coalesced
    Td[n] = b;
}

__global__ __launch_bounds__(TPB) void edge_kernel(
        const int* __restrict__ src, const int* __restrict__ dst,
        const uint4n* __restrict__ Ts, const uint4n* __restrict__ Td,
        float* __restrict__ out, int E) {
    __shared__ __align__(16) float tile[TPB * EPT * ODIM];  // 36864 B
    int e0 = blockIdx.x * (TPB * EPT);
    int cnt = min(TPB * EPT, E - e0);
    int t = (int)threadIdx.x;
    if (cnt == TPB * EPT) {
        int si[EPT], di[EPT];
        #pragma unroll
        for (int j = 0; j < EPT; ++j) {
            si[j] = __builtin_nontemporal_load(src + e0 + j * TPB + t);
            di[j] = __builtin_nontemporal_load(dst + e0 + j * TPB + t);
        }
        uint4n gs[EPT], gd[EPT];
        #pragma unroll
        for (int j = 0; j < EPT; ++j) {  // 8 independent gathers in flight
            gs[j] = Ts[si[j]];
            gd[j] = Td[di[j]];
        }
        #pragma unroll
        for (int j = 0; j < EPT; ++j) {
            int qs[9], qd[9];
            unpack9(gs[j], qs);
            unpack9(gd[j], qd);
            #pragma unroll
            for (int k = 0; k < ODIM; ++k)
                tile[(j * TPB + t) * ODIM + k] = tanh_from_q(qs[k] + qd[k]);
        }
        __syncthreads();
        // 9216 floats = 2304 float4, contiguous, 16B-aligned
        float4n* o4 = (float4n*)(out + (size_t)e0 * ODIM);
        const float4n* t4 = (const float4n*)tile;
        #pragma unroll
        for (int i = 0; i < TPB * EPT * ODIM / 4 / TPB; ++i)  // 9 rounds
            __builtin_nontemporal_store(t4[i * TPB + t], o4 + i * TPB + t);
    } else {
        for (int e = e0 + t; e < e0 + cnt; e += TPB) {
            int qs[9], qd[9];
            unpack9(Ts[src[e]], qs);
            unpack9(Td[dst[e]], qd);
            #pragma unroll
            for (int k = 0; k < ODIM; ++k)
                out[(size_t)e * ODIM + k] = tanh_from_q(qs[k] + qd[k]);
        }
    }
}

// Fallback if workspace is too small for the tables: fully fused per-edge.
__global__ __launch_bounds__(TPB) void edge_fused_kernel(
        const int* __restrict__ src, const int* __restrict__ dst,
        const float* __restrict__ x, const int* __restrict__ nt,
        const float* __restrict__ W, float* __restrict__ out, int E) {
    __shared__ __align__(16) float tile[TPB * ODIM];
    int e0 = blockIdx.x * TPB;
    int cnt = min(TPB, E - e0);
    int e = e0 + (int)threadIdx.x;
    if ((int)threadIdx.x < cnt) {
        int s = src[e];
        int d = dst[e];
        float xs[32], xd[32];
        const float4* xsp = (const float4*)(x + (size_t)s * 32);
        const float4* xdp = (const float4*)(x + (size_t)d * 32);
        #pragma unroll
        for (int i = 0; i < 8; ++i) {
            float4 rs = xsp[i], rd = xdp[i];
            xs[4*i+0]=rs.x; xs[4*i+1]=rs.y; xs[4*i+2]=rs.z; xs[4*i+3]=rs.w;
            xd[4*i+0]=rd.x; xd[4*i+1]=rd.y; xd[4*i+2]=rd.z; xd[4*i+3]=rd.w;
        }
        int ts = nt[s], td = nt[d];
        #pragma unroll
        for (int o = 0; o < ODIM; ++o) {
            const float* wr = W + o * INF;
            float acc = wr[64 + ts] + wr[68 + td];
            #pragma unroll
            for (int f = 0; f < 32; ++f)
                acc += xs[f] * wr[f] + xd[f] * wr[32 + f];
            float ex = __expf(2.0f * acc);
            tile[threadIdx.x * ODIM + o] =
                1.0f - 2.0f * __builtin_amdgcn_rcpf(ex + 1.0f);
        }
    }
    __syncthreads();
    if (cnt == TPB) {
        float4* o4 = (float4*)(out + (size_t)e0 * ODIM);
        const float4* t4 = (const float4*)tile;
        for (int i = threadIdx.x; i < TPB * ODIM / 4; i += TPB)
            o4[i] = t4[i];
    } else {
        for (int i = threadIdx.x; i < cnt * ODIM; i += TPB)
            out[(size_t)e0 * ODIM + i] = tile[i];
    }
}

extern "C" void kernel_launch(void* const* d_in, const int* in_sizes, int n_in,
                              void* d_out, int out_size, void* d_ws, size_t ws_size,
                              hipStream_t stream) {
    const float* x  = (const float*)d_in[0];
    const int*   ei = (const int*)d_in[1];   // [2, E]
    const int*   nt = (const int*)d_in[2];   // [N]
    const float* W  = (const float*)d_in[3]; // [9, 72]
    float* out = (float*)d_out;

    int N = in_sizes[2];
    int E = in_sizes[1] / 2;
    const int* src = ei;
    const int* dst = ei + E;

    size_t tbl = (size_t)N * 16;   // 1.6 MB per direction
    if (ws_size >= 2 * tbl) {
        uint4n* Ts = (uint4n*)d_ws;
        uint4n* Td = (uint4n*)((char*)d_ws + tbl);
        node_proj_kernel<<<(N + TPB - 1) / TPB, TPB, 0, stream>>>(x, nt, W, Ts, Td, N);
        int eb = TPB * EPT;
        edge_kernel<<<(E + eb - 1) / eb, TPB, 0, stream>>>(src, dst, Ts, Td, out, E);
    } else {
        edge_fused_kernel<<<(E + TPB - 1) / TPB, TPB, 0, stream>>>(src, dst, x, nt, W, out, E);
    }
}

// Round 8
// 113.962 us; speedup vs baseline: 1.0245x; 1.0245x over previous
//
#include <hip/hip_runtime.h>
#include <hip/hip_bf16.h>
#include <hip/hip_fp16.h>

// NodeTypeConcatSheafLearner: out[e] = tanh(concat(x[src],x[dst],oh[src],oh[dst]) @ W^T)
// Factorized: per-node projections quantized to 9 x 14-bit fixed-point
// (scale 128) packed into ONE 16-byte row per node per direction.
// Tables Ts, Td are 1.6 MB each (3.2 MB total) -> L2-resident per XCD; each
// edge does exactly TWO aligned global_load_dwordx4 gathers (one line each).
// Edge kernel: EPT=2 edges/thread (strided by TPB) -> 4 independent gathers
// in flight per thread, while LDS stays at 18.4 KB/block so occupancy holds
// at 8 blocks/CU (32 waves, both LDS- and wave-slot-saturated). R7 showed
// EPT=4 (36.9 KB LDS -> 4 blocks/CU) loses more TLP than the ILP gains.
// Error bound: quant 0.5/128 per operand, exact int add -> |out err| <= 1/128.

#define ODIM 9      // 3*3 output maps per edge
#define INF 72      // 2*32 + 2*4 input features of W rows
#define TPB 256
#define EPT 2       // edges per thread in edge_kernel
#define QSCALE 128.0f

typedef unsigned int uint4n __attribute__((ext_vector_type(4)));
typedef float float4n __attribute__((ext_vector_type(4)));

// tanh(q/128) = 1 - 2/(exp2(q*c)+1), c = 2*log2(e)/128
#define TANH_C (2.0f * 1.4426950408889634f / QSCALE)

__device__ __forceinline__ float tanh_from_q(int q) {
    float e = __builtin_exp2f((float)q * TANH_C);
    return 1.0f - 2.0f * __builtin_amdgcn_rcpf(e + 1.0f);
}

__device__ __forceinline__ int quant14(float v) {
    int q = __float2int_rn(v * QSCALE);
    return min(max(q, -8191), 8191);
}

__device__ __forceinline__ unsigned pk(int lo, int hi, unsigned nib) {
    return (unsigned)(lo & 0x3fff) | ((unsigned)(hi & 0x3fff) << 14) | (nib << 28);
}

__device__ __forceinline__ void unpack9(uint4n r, int* q) {
    q[0] = ((int)(r.x << 18)) >> 18;
    q[1] = ((int)(r.x <<  4)) >> 18;
    q[2] = ((int)(r.y << 18)) >> 18;
    q[3] = ((int)(r.y <<  4)) >> 18;
    q[4] = ((int)(r.z << 18)) >> 18;
    q[5] = ((int)(r.z <<  4)) >> 18;
    q[6] = ((int)(r.w << 18)) >> 18;
    q[7] = ((int)(r.w <<  4)) >> 18;
    unsigned u = (r.x >> 28) | ((r.y >> 28) << 4) |
                 ((r.z >> 28) << 8) | ((r.w >> 28) << 12);
    q[8] = ((int)(u << 18)) >> 18;
}

__global__ __launch_bounds__(TPB) void node_proj_kernel(
        const float* __restrict__ x, const int* __restrict__ nt,
        const float* __restrict__ W, uint4n* __restrict__ Ts,
        uint4n* __restrict__ Td, int N) {
    int n = blockIdx.x * TPB + threadIdx.x;
    if (n >= N) return;
    float xv[32];
    const float4n* xp = (const float4n*)(x + (size_t)n * 32);
    #pragma unroll
    for (int i = 0; i < 8; ++i) {
        float4n r = __builtin_nontemporal_load(xp + i);
        xv[4*i+0] = r.x; xv[4*i+1] = r.y; xv[4*i+2] = r.z; xv[4*i+3] = r.w;
    }
    int ty = nt[n];
    int qs[9], qd[9];
    #pragma unroll
    for (int o = 0; o < ODIM; ++o) {
        const float* wr = W + o * INF;  // wave-uniform base -> scalar loads
        float s1 = wr[64 + ty];         // one-hot(src type) contribution
        float s2 = wr[68 + ty];         // one-hot(dst type) contribution
        #pragma unroll
        for (int f = 0; f < 32; ++f) {
            s1 += xv[f] * wr[f];
            s2 += xv[f] * wr[32 + f];
        }
        qs[o] = quant14(s1);
        qd[o] = quant14(s2);
    }
    uint4n a, b;
    a.x = pk(qs[0], qs[1],  (unsigned)qs[8]        & 0xf);
    a.y = pk(qs[2], qs[3], ((unsigned)qs[8] >>  4) & 0xf);
    a.z = pk(qs[4], qs[5], ((unsigned)qs[8] >>  8) & 0xf);
    a.w = pk(qs[6], qs[7], ((unsigned)qs[8] >> 12) & 0x3);
    b.x = pk(qd[0], qd[1],  (unsigned)qd[8]        & 0xf);
    b.y = pk(qd[2], qd[3], ((unsigned)qd[8] >>  4) & 0xf);
    b.z = pk(qd[4], qd[5], ((unsigned)qd[8] >>  8) & 0xf);
    b.w = pk(qd[6], qd[7], ((unsigned)qd[8] >> 12) & 0x3);
    Ts[n] = a;  // 16B/thread, fully coalesced
    Td[n] = b;
}

__global__ __launch_bounds__(TPB) void edge_kernel(
        const int* __restrict__ src, const int* __restrict__ dst,
        const uint4n* __restrict__ Ts, const uint4n* __restrict__ Td,
        float* __restrict__ out, int E) {
    __shared__ __align__(16) float tile[TPB * EPT * ODIM];  // 18432 B
    int e0 = blockIdx.x * (TPB * EPT);
    int cnt = min(TPB * EPT, E - e0);
    int t = (int)threadIdx.x;
    if (cnt == TPB * EPT) {
        int si[EPT], di[EPT];
        #pragma unroll
        for (int j = 0; j < EPT; ++j) {
            si[j] = __builtin_nontemporal_load(src + e0 + j * TPB + t);
            di[j] = __builtin_nontemporal_load(dst + e0 + j * TPB + t);
        }
        uint4n gs[EPT], gd[EPT];
        #pragma unroll
        for (int j = 0; j < EPT; ++j) {  // 4 independent gathers in flight
            gs[j] = Ts[si[j]];
            gd[j] = Td[di[j]];
        }
        #pragma unroll
        for (int j = 0; j < EPT; ++j) {
            int qs[9], qd[9];
            unpack9(gs[j], qs);
            unpack9(gd[j], qd);
            #pragma unroll
            for (int k = 0; k < ODIM; ++k)
                tile[(j * TPB + t) * ODIM + k] = tanh_from_q(qs[k] + qd[k]);
        }
        __syncthreads();
        // 4608 floats = 1152 float4, contiguous, 16B-aligned
        float4n* o4 = (float4n*)(out + (size_t)e0 * ODIM);
        const float4n* t4 = (const float4n*)tile;
        #pragma unroll
        for (int i = 0; i < TPB * EPT * ODIM / 4 / TPB; ++i)  // 4.5 -> 4 full
            __builtin_nontemporal_store(t4[i * TPB + t], o4 + i * TPB + t);
        // remaining half-round (1152 - 4*256 = 128 float4)
        if (t < (TPB * EPT * ODIM / 4) - 4 * TPB)
            __builtin_nontemporal_store(t4[4 * TPB + t], o4 + 4 * TPB + t);
    } else {
        for (int e = e0 + t; e < e0 + cnt; e += TPB) {
            int qs[9], qd[9];
            unpack9(Ts[src[e]], qs);
            unpack9(Td[dst[e]], qd);
            #pragma unroll
            for (int k = 0; k < ODIM; ++k)
                out[(size_t)e * ODIM + k] = tanh_from_q(qs[k] + qd[k]);
        }
    }
}

// Fallback if workspace is too small for the tables: fully fused per-edge.
__global__ __launch_bounds__(TPB) void edge_fused_kernel(
        const int* __restrict__ src, const int* __restrict__ dst,
        const float* __restrict__ x, const int* __restrict__ nt,
        const float* __restrict__ W, float* __restrict__ out, int E) {
    __shared__ __align__(16) float tile[TPB * ODIM];
    int e0 = blockIdx.x * TPB;
    int cnt = min(TPB, E - e0);
    int e = e0 + (int)threadIdx.x;
    if ((int)threadIdx.x < cnt) {
        int s = src[e];
        int d = dst[e];
        float xs[32], xd[32];
        const float4* xsp = (const float4*)(x + (size_t)s * 32);
        const float4* xdp = (const float4*)(x + (size_t)d * 32);
        #pragma unroll
        for (int i = 0; i < 8; ++i) {
            float4 rs = xsp[i], rd = xdp[i];
            xs[4*i+0]=rs.x; xs[4*i+1]=rs.y; xs[4*i+2]=rs.z; xs[4*i+3]=rs.w;
            xd[4*i+0]=rd.x; xd[4*i+1]=rd.y; xd[4*i+2]=rd.z; xd[4*i+3]=rd.w;
        }
        int ts = nt[s], td = nt[d];
        #pragma unroll
        for (int o = 0; o < ODIM; ++o) {
            const float* wr = W + o * INF;
            float acc = wr[64 + ts] + wr[68 + td];
            #pragma unroll
            for (int f = 0; f < 32; ++f)
                acc += xs[f] * wr[f] + xd[f] * wr[32 + f];
            float ex = __expf(2.0f * acc);
            tile[threadIdx.x * ODIM + o] =
                1.0f - 2.0f * __builtin_amdgcn_rcpf(ex + 1.0f);
        }
    }
    __syncthreads();
    if (cnt == TPB) {
        float4* o4 = (float4*)(out + (size_t)e0 * ODIM);
        const float4* t4 = (const float4*)tile;
        for (int i = threadIdx.x; i < TPB * ODIM / 4; i += TPB)
            o4[i] = t4[i];
    } else {
        for (int i = threadIdx.x; i < cnt * ODIM; i += TPB)
            out[(size_t)e0 * ODIM + i] = tile[i];
    }
}

extern "C" void kernel_launch(void* const* d_in, const int* in_sizes, int n_in,
                              void* d_out, int out_size, void* d_ws, size_t ws_size,
                              hipStream_t stream) {
    const float* x  = (const float*)d_in[0];
    const int*   ei = (const int*)d_in[1];   // [2, E]
    const int*   nt = (const int*)d_in[2];   // [N]
    const float* W  = (const float*)d_in[3]; // [9, 72]
    float* out = (float*)d_out;

    int N = in_sizes[2];
    int E = in_sizes[1] / 2;
    const int* src = ei;
    const int* dst = ei + E;

    size_t tbl = (size_t)N * 16;   // 1.6 MB per direction
    if (ws_size >= 2 * tbl) {
        uint4n* Ts = (uint4n*)d_ws;
        uint4n* Td = (uint4n*)((char*)d_ws + tbl);
        node_proj_kernel<<<(N + TPB - 1) / TPB, TPB, 0, stream>>>(x, nt, W, Ts, Td, N);
        int eb = TPB * EPT;
        edge_kernel<<<(E + eb - 1) / eb, TPB, 0, stream>>>(src, dst, Ts, Td, out, E);
    } else {
        edge_fused_kernel<<<(E + TPB - 1) / TPB, TPB, 0, stream>>>(src, dst, x, nt, W, out, E);
    }
}